// Round 1
// baseline (3928.934 us; speedup 1.0000x reference)
//
#include <hip/hip_runtime.h>
#include <math.h>

#define MAXNORM 0.996f      // (1 - 4e-3) / sqrt(-K)
#define MINV    1e-15f
#define CLIPV   0.99999988f // f32(1 - 1e-7)

__device__ __forceinline__ float waveReduce(float v) {
#pragma unroll
    for (int off = 32; off; off >>= 1) v += __shfl_down(v, off, 64);
    return v;
}

__device__ __forceinline__ float artanh_clip(float z) {
    z = fminf(z, CLIPV);
    return 0.5f * logf((1.0f + z) / (1.0f - z));
}

// ---------------- weight prep: W [ncol][nk] -> packed WT4 so that
// float4 load (k4*ncol + j) gives W[j][4k..4k+3] ----------------
__global__ void transpose_pack4(const float* __restrict__ W, float* __restrict__ WT4,
                                int ncol, int nk) {
    int idx = blockIdx.x * 256 + threadIdx.x;
    if (idx >= ncol * nk) return;
    int j = idx / nk, k = idx - j * nk;
    WT4[((size_t)(k >> 2) * ncol + j) * 4 + (k & 3)] = W[idx];
}

// ---------------- kb = expmap0(b); also y2 = ||kb||^2 ----------------
template <int D>
__global__ __launch_bounds__(D) void kb_kernel(const float* __restrict__ b,
                                               float* __restrict__ kb,
                                               float* __restrict__ y2out) {
    constexpr int NW = D / 64;
    __shared__ float red[NW];
    int j = threadIdx.x;
    float u = b[j];
    float ss = waveReduce(u * u);
    if ((j & 63) == 0) red[j >> 6] = ss;
    __syncthreads();
    float tot = 0;
#pragma unroll
    for (int w = 0; w < NW; ++w) tot += red[w];
    float un = fmaxf(sqrtf(tot), MINV);
    float t = tanhf(un);
    float s = t / un;
    if (t > MAXNORM) s *= MAXNORM / t;
    float v = u * s;
    kb[j] = v;
    float ss2 = waveReduce(v * v);
    __syncthreads();
    if ((j & 63) == 0) red[j >> 6] = ss2;
    __syncthreads();
    if (j == 0) {
        float t2 = 0;
        for (int w = 0; w < NW; ++w) t2 += red[w];
        y2out[0] = t2;
    }
}

// ---------------- per-row expmap0 (one row per block) ----------------
template <int D>
__global__ __launch_bounds__(D) void expmap0_kernel(const float* __restrict__ in,
                                                    float* __restrict__ out, int n) {
    constexpr int NW = D / 64;
    __shared__ float red[NW];
    int row = blockIdx.x;
    if (row >= n) return;
    int j = threadIdx.x;
    float u = in[(size_t)row * D + j];
    float ss = waveReduce(u * u);
    if ((j & 63) == 0) red[j >> 6] = ss;
    __syncthreads();
    float tot = 0;
#pragma unroll
    for (int w = 0; w < NW; ++w) tot += red[w];
    float un = fmaxf(sqrtf(tot), MINV);
    float t = tanhf(un);
    float s = t / un;
    if (t > MAXNORM) s *= MAXNORM / t;
    out[(size_t)row * D + j] = u * s;
}

// ---------------- fused: mv = X @ W^T ; mobius_matvec post-scale ;
// mobius_add(bias kb) ; logmap0  -> XT  (8 rows per block) ----------------
template <int NCOL>
__global__ __launch_bounds__(NCOL) void fused_layer_kernel(
        const float* __restrict__ X,   // [n][256]
        const float* __restrict__ WT,  // packed, see transpose_pack4
        const float* __restrict__ kb,  // [NCOL]
        const float* __restrict__ y2p, // scalar ||kb||^2
        float* __restrict__ XT,        // [n][NCOL]
        int n) {
    constexpr int NK = 256, ROWS = 8;
    constexpr int NW = NCOL / 64;
    constexpr int RPW = ROWS / NW;
    __shared__ float sA[ROWS][NK];
    __shared__ float sV[ROWS][NCOL];
    __shared__ float sS[ROWS][4];

    const int j = threadIdx.x;
    const int wid = j >> 6, lid = j & 63;
    const size_t r0 = (size_t)blockIdx.x * ROWS;

    for (int idx = j; idx < ROWS * NK; idx += NCOL) {
        int r = idx >> 8, k = idx & (NK - 1);
        sA[r][k] = (r0 + r < (size_t)n) ? X[(r0 + r) * NK + k] : 0.0f;
    }
    __syncthreads();

    float acc[ROWS] = {};
    const float4* wp4 = reinterpret_cast<const float4*>(WT);
    for (int k4 = 0; k4 < NK / 4; ++k4) {
        const float4 w = wp4[(size_t)k4 * NCOL + j];
#pragma unroll
        for (int r = 0; r < ROWS; ++r) {
            const float4 a = *reinterpret_cast<const float4*>(&sA[r][k4 * 4]);
            acc[r] = fmaf(a.x, w.x, fmaf(a.y, w.y, fmaf(a.z, w.z, fmaf(a.w, w.w, acc[r]))));
        }
    }
#pragma unroll
    for (int r = 0; r < ROWS; ++r) sV[r][j] = acc[r];
    __syncthreads();

    const float y2 = *y2p;
    // reductions: ||x||^2, ||mv||^2, <mv,kb>
#pragma unroll
    for (int q = 0; q < RPW; ++q) {
        const int r = wid * RPW + q;
        float xs = 0, ms = 0, xy = 0;
#pragma unroll
        for (int t = lid; t < NK; t += 64) xs += sA[r][t] * sA[r][t];
#pragma unroll
        for (int t = lid; t < NCOL; t += 64) {
            float m = sV[r][t];
            ms += m * m;
            xy += m * kb[t];
        }
        xs = waveReduce(xs);
        ms = waveReduce(ms);
        xy = waveReduce(xy);
        if (lid == 0) {
            float xn  = fmaxf(sqrtf(xs), MINV);
            float mvn = fmaxf(sqrtf(ms), MINV);
            float t1  = tanhf(mvn / xn * artanh_clip(xn));
            float s1  = t1 / mvn;
            if (t1 > MAXNORM) s1 *= MAXNORM / t1;   // project(res)
            float rn  = s1 * mvn;                   // ||res||
            float x2  = rn * rn;
            float xyr = s1 * xy;
            float ca  = 1.0f + 2.0f * xyr + y2;
            float cb  = 1.0f - x2;
            float den = fmaxf(1.0f + 2.0f * xyr + x2 * y2, MINV);
            sS[r][0] = ca * s1 / den;  // coeff on mv
            sS[r][1] = cb / den;       // coeff on kb
        }
    }
    __syncthreads();
    // ||mobius_add output|| -> project + logmap0 scale
#pragma unroll
    for (int q = 0; q < RPW; ++q) {
        const int r = wid * RPW + q;
        const float p = sS[r][0], qq = sS[r][1];
        float os = 0;
#pragma unroll
        for (int t = lid; t < NCOL; t += 64) {
            float o = p * sV[r][t] + qq * kb[t];
            os += o * o;
        }
        os = waveReduce(os);
        if (lid == 0) {
            float on = fmaxf(sqrtf(os), MINV);
            float s2 = (on > MAXNORM) ? (MAXNORM / on) : 1.0f; // project
            float yn = fmaxf(on * s2, MINV);
            sS[r][2] = artanh_clip(yn) / yn * s2;              // logmap0
        }
    }
    __syncthreads();
#pragma unroll
    for (int r = 0; r < ROWS; ++r) {
        if (r0 + r < (size_t)n) {
            float p = sS[r][0], qq = sS[r][1], f = sS[r][2];
            XT[(r0 + r) * NCOL + j] = f * (p * sV[r][j] + qq * kb[j]);
        }
    }
}

// ---------------- degrees ----------------
__global__ void deg_init(float* __restrict__ deg, int n) {
    int i = blockIdx.x * 256 + threadIdx.x;
    if (i < n) deg[i] = 1.0f;  // self loop
}
__global__ void deg_count(const int* __restrict__ col, int E, float* __restrict__ deg) {
    int e = blockIdx.x * 256 + threadIdx.x;
    if (e < E) atomicAdd(&deg[col[e]], 1.0f);
}
__global__ void deg_to_dis(float* __restrict__ deg, int n) {
    int i = blockIdx.x * 256 + threadIdx.x;
    if (i < n) deg[i] = 1.0f / sqrtf(deg[i]);
}

// ---------------- edge aggregation: out[col] += dis[r]*dis[c]*xt[row] ----------------
template <int D>
__global__ __launch_bounds__(256) void aggregate_kernel(
        const float* __restrict__ xt, const float* __restrict__ dis,
        const int* __restrict__ row, const int* __restrict__ col,
        int E, int n, float* __restrict__ out) {
    int e = blockIdx.x * 4 + (threadIdx.x >> 6);
    if (e >= E + n) return;
    int lid = threadIdx.x & 63;
    int r, c;
    if (e < E) { r = row[e]; c = col[e]; } else { r = e - E; c = r; }
    float w = dis[r] * dis[c];
    constexpr int PER = D / 64;  // 4 or 2 floats per lane
    const float* src = xt + (size_t)r * D + lid * PER;
    float* dst = out + (size_t)c * D + lid * PER;
#pragma unroll
    for (int q = 0; q < PER; ++q) atomicAdd(dst + q, w * src[q]);
}

extern "C" void kernel_launch(void* const* d_in, const int* in_sizes, int n_in,
                              void* d_out, int out_size, void* d_ws, size_t ws_size,
                              hipStream_t stream) {
    const float* x  = (const float*)d_in[0];
    const float* W1 = (const float*)d_in[1];
    const float* b1 = (const float*)d_in[2];
    const float* W2 = (const float*)d_in[3];
    const float* b2 = (const float*)d_in[4];
    const int*   ei = (const int*)d_in[5];

    const int N = in_sizes[0] / 256;
    const int E = in_sizes[5] / 2;
    const int* row = ei;
    const int* col = ei + E;

    float* ws = (float*)d_ws;
    size_t off = 0;
    float* A   = ws + off; off += (size_t)N * 256;
    float* C   = ws + off; off += (size_t)N * 256;
    float* W1T = ws + off; off += 256 * 256;
    float* W2T = ws + off; off += 128 * 256;
    float* kb1 = ws + off; off += 256;
    float* kb2 = ws + off; off += 128;
    float* y2s = ws + off; off += 4;
    float* deg = ws + off; off += N;

    // weight prep + bias maps
    transpose_pack4<<<(256 * 256 + 255) / 256, 256, 0, stream>>>(W1, W1T, 256, 256);
    transpose_pack4<<<(128 * 256 + 255) / 256, 256, 0, stream>>>(W2, W2T, 128, 256);
    kb_kernel<256><<<1, 256, 0, stream>>>(b1, kb1, y2s);
    kb_kernel<128><<<1, 128, 0, stream>>>(b2, kb2, y2s + 1);

    // degrees -> dis (in place)
    deg_init<<<(N + 255) / 256, 256, 0, stream>>>(deg, N);
    deg_count<<<(E + 255) / 256, 256, 0, stream>>>(col, E, deg);
    deg_to_dis<<<(N + 255) / 256, 256, 0, stream>>>(deg, N);

    // x0 = expmap0(x)
    expmap0_kernel<256><<<N, 256, 0, stream>>>(x, A, N);

    // ----- layer 1 (D=256) -----
    fused_layer_kernel<256><<<(N + 7) / 8, 256, 0, stream>>>(A, W1T, kb1, y2s, C, N);
    hipMemsetAsync(A, 0, (size_t)N * 256 * sizeof(float), stream);
    aggregate_kernel<256><<<(E + N + 3) / 4, 256, 0, stream>>>(C, deg, row, col, E, N, A);
    expmap0_kernel<256><<<N, 256, 0, stream>>>(A, A, N);  // h (in place)

    // ----- layer 2 (D=128) -----
    fused_layer_kernel<128><<<(N + 7) / 8, 128, 0, stream>>>(A, W2T, kb2, y2s + 1, C, N);
    hipMemsetAsync(A, 0, (size_t)N * 128 * sizeof(float), stream);
    aggregate_kernel<128><<<(E + N + 3) / 4, 256, 0, stream>>>(C, deg, row, col, E, N, A);
    expmap0_kernel<128><<<N, 128, 0, stream>>>(A, (float*)d_out, N);
}

// Round 2
// 651.786 us; speedup vs baseline: 6.0279x; 6.0279x over previous
//
#include <hip/hip_runtime.h>
#include <math.h>

#define MAXNORM 0.996f      // (1 - 4e-3) / sqrt(-K)
#define MINV    1e-15f
#define CLIPV   0.99999988f // f32(1 - 1e-7)

__device__ __forceinline__ float waveReduce(float v) {
#pragma unroll
    for (int off = 32; off; off >>= 1) v += __shfl_down(v, off, 64);
    return v;
}

__device__ __forceinline__ float waveAllSum(float v) {
#pragma unroll
    for (int off = 32; off; off >>= 1) v += __shfl_xor(v, off, 64);
    return v;
}

__device__ __forceinline__ float artanh_clip(float z) {
    z = fminf(z, CLIPV);
    return 0.5f * logf((1.0f + z) / (1.0f - z));
}

// ---------------- weight prep: W [ncol][nk] -> packed WT4 so that
// float4 load (k4*ncol + j) gives W[j][4k..4k+3] ----------------
__global__ void transpose_pack4(const float* __restrict__ W, float* __restrict__ WT4,
                                int ncol, int nk) {
    int idx = blockIdx.x * 256 + threadIdx.x;
    if (idx >= ncol * nk) return;
    int j = idx / nk, k = idx - j * nk;
    WT4[((size_t)(k >> 2) * ncol + j) * 4 + (k & 3)] = W[idx];
}

// ---------------- kb = expmap0(b); also y2 = ||kb||^2 ----------------
template <int D>
__global__ __launch_bounds__(D) void kb_kernel(const float* __restrict__ b,
                                               float* __restrict__ kb,
                                               float* __restrict__ y2out) {
    constexpr int NW = D / 64;
    __shared__ float red[NW];
    int j = threadIdx.x;
    float u = b[j];
    float ss = waveReduce(u * u);
    if ((j & 63) == 0) red[j >> 6] = ss;
    __syncthreads();
    float tot = 0;
#pragma unroll
    for (int w = 0; w < NW; ++w) tot += red[w];
    float un = fmaxf(sqrtf(tot), MINV);
    float t = tanhf(un);
    float s = t / un;
    if (t > MAXNORM) s *= MAXNORM / t;
    float v = u * s;
    kb[j] = v;
    float ss2 = waveReduce(v * v);
    __syncthreads();
    if ((j & 63) == 0) red[j >> 6] = ss2;
    __syncthreads();
    if (j == 0) {
        float t2 = 0;
        for (int w = 0; w < NW; ++w) t2 += red[w];
        y2out[0] = t2;
    }
}

// ---------------- per-row expmap0 (one row per block) ----------------
template <int D>
__global__ __launch_bounds__(D) void expmap0_kernel(const float* __restrict__ in,
                                                    float* __restrict__ out, int n) {
    constexpr int NW = D / 64;
    __shared__ float red[NW];
    int row = blockIdx.x;
    if (row >= n) return;
    int j = threadIdx.x;
    float u = in[(size_t)row * D + j];
    float ss = waveReduce(u * u);
    if ((j & 63) == 0) red[j >> 6] = ss;
    __syncthreads();
    float tot = 0;
#pragma unroll
    for (int w = 0; w < NW; ++w) tot += red[w];
    float un = fmaxf(sqrtf(tot), MINV);
    float t = tanhf(un);
    float s = t / un;
    if (t > MAXNORM) s *= MAXNORM / t;
    out[(size_t)row * D + j] = u * s;
}

// ---------------- fused: mv = X @ W^T ; mobius_matvec post-scale ;
// mobius_add(bias kb) ; logmap0  -> XT  (8 rows per block) ----------------
template <int NCOL>
__global__ __launch_bounds__(NCOL) void fused_layer_kernel(
        const float* __restrict__ X,   // [n][256]
        const float* __restrict__ WT,  // packed, see transpose_pack4
        const float* __restrict__ kb,  // [NCOL]
        const float* __restrict__ y2p, // scalar ||kb||^2
        float* __restrict__ XT,        // [n][NCOL]
        int n) {
    constexpr int NK = 256, ROWS = 8;
    constexpr int NW = NCOL / 64;
    constexpr int RPW = ROWS / NW;
    __shared__ float sA[ROWS][NK];
    __shared__ float sV[ROWS][NCOL];
    __shared__ float sS[ROWS][4];

    const int j = threadIdx.x;
    const int wid = j >> 6, lid = j & 63;
    const size_t r0 = (size_t)blockIdx.x * ROWS;

    for (int idx = j; idx < ROWS * NK; idx += NCOL) {
        int r = idx >> 8, k = idx & (NK - 1);
        sA[r][k] = (r0 + r < (size_t)n) ? X[(r0 + r) * NK + k] : 0.0f;
    }
    __syncthreads();

    float acc[ROWS] = {};
    const float4* wp4 = reinterpret_cast<const float4*>(WT);
    for (int k4 = 0; k4 < NK / 4; ++k4) {
        const float4 w = wp4[(size_t)k4 * NCOL + j];
#pragma unroll
        for (int r = 0; r < ROWS; ++r) {
            const float4 a = *reinterpret_cast<const float4*>(&sA[r][k4 * 4]);
            acc[r] = fmaf(a.x, w.x, fmaf(a.y, w.y, fmaf(a.z, w.z, fmaf(a.w, w.w, acc[r]))));
        }
    }
#pragma unroll
    for (int r = 0; r < ROWS; ++r) sV[r][j] = acc[r];
    __syncthreads();

    const float y2 = *y2p;
    // reductions: ||x||^2, ||mv||^2, <mv,kb>
#pragma unroll
    for (int q = 0; q < RPW; ++q) {
        const int r = wid * RPW + q;
        float xs = 0, ms = 0, xy = 0;
#pragma unroll
        for (int t = lid; t < NK; t += 64) xs += sA[r][t] * sA[r][t];
#pragma unroll
        for (int t = lid; t < NCOL; t += 64) {
            float m = sV[r][t];
            ms += m * m;
            xy += m * kb[t];
        }
        xs = waveReduce(xs);
        ms = waveReduce(ms);
        xy = waveReduce(xy);
        if (lid == 0) {
            float xn  = fmaxf(sqrtf(xs), MINV);
            float mvn = fmaxf(sqrtf(ms), MINV);
            float t1  = tanhf(mvn / xn * artanh_clip(xn));
            float s1  = t1 / mvn;
            if (t1 > MAXNORM) s1 *= MAXNORM / t1;   // project(res)
            float rn  = s1 * mvn;                   // ||res||
            float x2  = rn * rn;
            float xyr = s1 * xy;
            float ca  = 1.0f + 2.0f * xyr + y2;
            float cb  = 1.0f - x2;
            float den = fmaxf(1.0f + 2.0f * xyr + x2 * y2, MINV);
            sS[r][0] = ca * s1 / den;  // coeff on mv
            sS[r][1] = cb / den;       // coeff on kb
        }
    }
    __syncthreads();
    // ||mobius_add output|| -> project + logmap0 scale
#pragma unroll
    for (int q = 0; q < RPW; ++q) {
        const int r = wid * RPW + q;
        const float p = sS[r][0], qq = sS[r][1];
        float os = 0;
#pragma unroll
        for (int t = lid; t < NCOL; t += 64) {
            float o = p * sV[r][t] + qq * kb[t];
            os += o * o;
        }
        os = waveReduce(os);
        if (lid == 0) {
            float on = fmaxf(sqrtf(os), MINV);
            float s2 = (on > MAXNORM) ? (MAXNORM / on) : 1.0f; // project
            float yn = fmaxf(on * s2, MINV);
            sS[r][2] = artanh_clip(yn) / yn * s2;              // logmap0
        }
    }
    __syncthreads();
#pragma unroll
    for (int r = 0; r < ROWS; ++r) {
        if (r0 + r < (size_t)n) {
            float p = sS[r][0], qq = sS[r][1], f = sS[r][2];
            XT[(r0 + r) * NCOL + j] = f * (p * sV[r][j] + qq * kb[j]);
        }
    }
}

// ---------------- CSR build ----------------
__global__ void count_in_kernel(const int* __restrict__ col, int E, int* __restrict__ icnt) {
    int e = blockIdx.x * 256 + threadIdx.x;
    if (e < E) atomicAdd(&icnt[col[e]], 1);
}

__global__ __launch_bounds__(1024) void exscan_kernel(const int* __restrict__ cnt,
                                                      int* __restrict__ offs, int n) {
    __shared__ int sdata[1024];
    __shared__ int carry;
    const int tid = threadIdx.x;
    if (tid == 0) carry = 0;
    __syncthreads();
    for (int base = 0; base < n; base += 1024) {
        const int i = base + tid;
        int v = (i < n) ? cnt[i] : 0;
        sdata[tid] = v;
        __syncthreads();
        for (int off = 1; off < 1024; off <<= 1) {
            int t = (tid >= off) ? sdata[tid - off] : 0;
            __syncthreads();
            sdata[tid] += t;
            __syncthreads();
        }
        int incl = sdata[tid];
        if (i < n) offs[i] = carry + incl - v;
        int blocksum = sdata[1023];
        __syncthreads();
        if (tid == 0) carry += blocksum;
        __syncthreads();
    }
}

// dis = rsqrt(icnt+1); cursor = offs
__global__ void dis_kernel(const int* __restrict__ icnt, const int* __restrict__ offs,
                           float* __restrict__ dis, int* __restrict__ cursor, int n) {
    int i = blockIdx.x * 256 + threadIdx.x;
    if (i < n) {
        dis[i] = rsqrtf((float)(icnt[i] + 1));
        cursor[i] = offs[i];
    }
}

__global__ void csr_scatter(const int* __restrict__ row, const int* __restrict__ col,
                            const float* __restrict__ dis, int E,
                            int* __restrict__ cursor, int* __restrict__ csr_src,
                            float* __restrict__ csr_w) {
    int e = blockIdx.x * 256 + threadIdx.x;
    if (e >= E) return;
    int r = row[e], c = col[e];
    int p = atomicAdd(&cursor[c], 1);
    csr_src[p] = r;
    csr_w[p] = dis[r] * dis[c];
}

// ---------------- gather + expmap0: one wave per node ----------------
template <int D>
__global__ __launch_bounds__(256) void gather_expmap_kernel(
        const float* __restrict__ xt, const float* __restrict__ dis,
        const int* __restrict__ offs, const int* __restrict__ icnt,
        const int* __restrict__ csr_src, const float* __restrict__ csr_w,
        int n, float* __restrict__ out) {
    constexpr int PER = D / 64;  // 4 (D=256) or 2 (D=128)
    int node = blockIdx.x * 4 + (threadIdx.x >> 6);
    if (node >= n) return;
    int lid = threadIdx.x & 63;

    float acc[PER];
    // self loop weight = dis[c]^2
    float wc = dis[node];
    float wself = wc * wc;
    {
        const float* sp = xt + (size_t)node * D + lid * PER;
        if constexpr (PER == 4) {
            const float4 v = *reinterpret_cast<const float4*>(sp);
            acc[0] = wself * v.x; acc[1] = wself * v.y;
            acc[2] = wself * v.z; acc[3] = wself * v.w;
        } else {
            const float2 v = *reinterpret_cast<const float2*>(sp);
            acc[0] = wself * v.x; acc[1] = wself * v.y;
        }
    }

    const int s = offs[node];
    const int e = s + icnt[node];
    int p = s;
    for (; p + 1 < e; p += 2) {
        const int r0v = csr_src[p], r1v = csr_src[p + 1];
        const float w0 = csr_w[p], w1 = csr_w[p + 1];
        const float* s0 = xt + (size_t)r0v * D + lid * PER;
        const float* s1 = xt + (size_t)r1v * D + lid * PER;
        if constexpr (PER == 4) {
            const float4 v0 = *reinterpret_cast<const float4*>(s0);
            const float4 v1 = *reinterpret_cast<const float4*>(s1);
            acc[0] = fmaf(w0, v0.x, acc[0]); acc[1] = fmaf(w0, v0.y, acc[1]);
            acc[2] = fmaf(w0, v0.z, acc[2]); acc[3] = fmaf(w0, v0.w, acc[3]);
            acc[0] = fmaf(w1, v1.x, acc[0]); acc[1] = fmaf(w1, v1.y, acc[1]);
            acc[2] = fmaf(w1, v1.z, acc[2]); acc[3] = fmaf(w1, v1.w, acc[3]);
        } else {
            const float2 v0 = *reinterpret_cast<const float2*>(s0);
            const float2 v1 = *reinterpret_cast<const float2*>(s1);
            acc[0] = fmaf(w0, v0.x, acc[0]); acc[1] = fmaf(w0, v0.y, acc[1]);
            acc[0] = fmaf(w1, v1.x, acc[0]); acc[1] = fmaf(w1, v1.y, acc[1]);
        }
    }
    if (p < e) {
        const int rv = csr_src[p];
        const float w = csr_w[p];
        const float* sp = xt + (size_t)rv * D + lid * PER;
        if constexpr (PER == 4) {
            const float4 v = *reinterpret_cast<const float4*>(sp);
            acc[0] = fmaf(w, v.x, acc[0]); acc[1] = fmaf(w, v.y, acc[1]);
            acc[2] = fmaf(w, v.z, acc[2]); acc[3] = fmaf(w, v.w, acc[3]);
        } else {
            const float2 v = *reinterpret_cast<const float2*>(sp);
            acc[0] = fmaf(w, v.x, acc[0]); acc[1] = fmaf(w, v.y, acc[1]);
        }
    }

    // expmap0 in-register
    float ss = 0;
#pragma unroll
    for (int q = 0; q < PER; ++q) ss += acc[q] * acc[q];
    ss = waveAllSum(ss);
    float un = fmaxf(sqrtf(ss), MINV);
    float t = tanhf(un);
    float sc = t / un;
    if (t > MAXNORM) sc *= MAXNORM / t;

    float* op = out + (size_t)node * D + lid * PER;
    if constexpr (PER == 4) {
        float4 o;
        o.x = sc * acc[0]; o.y = sc * acc[1]; o.z = sc * acc[2]; o.w = sc * acc[3];
        *reinterpret_cast<float4*>(op) = o;
    } else {
        float2 o;
        o.x = sc * acc[0]; o.y = sc * acc[1];
        *reinterpret_cast<float2*>(op) = o;
    }
}

extern "C" void kernel_launch(void* const* d_in, const int* in_sizes, int n_in,
                              void* d_out, int out_size, void* d_ws, size_t ws_size,
                              hipStream_t stream) {
    const float* x  = (const float*)d_in[0];
    const float* W1 = (const float*)d_in[1];
    const float* b1 = (const float*)d_in[2];
    const float* W2 = (const float*)d_in[3];
    const float* b2 = (const float*)d_in[4];
    const int*   ei = (const int*)d_in[5];

    const int N = in_sizes[0] / 256;
    const int E = in_sizes[5] / 2;
    const int* row = ei;
    const int* col = ei + E;

    float* ws = (float*)d_ws;
    size_t off = 0;
    float* A    = ws + off; off += (size_t)N * 256;
    float* C    = ws + off; off += (size_t)N * 256;
    float* W1T  = ws + off; off += 256 * 256;
    float* W2T  = ws + off; off += 128 * 256;
    float* kb1  = ws + off; off += 256;
    float* kb2  = ws + off; off += 128;
    float* y2s  = ws + off; off += 4;
    float* dis  = ws + off; off += N;
    int*  icnt  = (int*)(ws + off); off += N;
    int*  offs  = (int*)(ws + off); off += N + 4;
    int*  cursor= (int*)(ws + off); off += N;
    int*  csrs  = (int*)(ws + off); off += E;
    float* csrw = ws + off; off += E;

    // weight prep + bias maps
    transpose_pack4<<<(256 * 256 + 255) / 256, 256, 0, stream>>>(W1, W1T, 256, 256);
    transpose_pack4<<<(128 * 256 + 255) / 256, 256, 0, stream>>>(W2, W2T, 128, 256);
    kb_kernel<256><<<1, 256, 0, stream>>>(b1, kb1, y2s);
    kb_kernel<128><<<1, 128, 0, stream>>>(b2, kb2, y2s + 1);

    // CSR build: in-degree -> exclusive scan -> scatter (row, weight)
    hipMemsetAsync(icnt, 0, (size_t)N * sizeof(int), stream);
    count_in_kernel<<<(E + 255) / 256, 256, 0, stream>>>(col, E, icnt);
    exscan_kernel<<<1, 1024, 0, stream>>>(icnt, offs, N);
    dis_kernel<<<(N + 255) / 256, 256, 0, stream>>>(icnt, offs, dis, cursor, N);
    csr_scatter<<<(E + 255) / 256, 256, 0, stream>>>(row, col, dis, E, cursor, csrs, csrw);

    // x0 = expmap0(x)
    expmap0_kernel<256><<<N, 256, 0, stream>>>(x, A, N);

    // ----- layer 1 (D=256) -----
    fused_layer_kernel<256><<<(N + 7) / 8, 256, 0, stream>>>(A, W1T, kb1, y2s, C, N);
    gather_expmap_kernel<256><<<(N + 3) / 4, 256, 0, stream>>>(C, dis, offs, icnt, csrs, csrw, N, A);

    // ----- layer 2 (D=128) -----
    fused_layer_kernel<128><<<(N + 7) / 8, 128, 0, stream>>>(A, W2T, kb2, y2s + 1, C, N);
    gather_expmap_kernel<128><<<(N + 3) / 4, 256, 0, stream>>>(C, dis, offs, icnt, csrs, csrw, N, (float*)d_out);
}

// Round 3
// 421.391 us; speedup vs baseline: 9.3237x; 1.5468x over previous
//
#include <hip/hip_runtime.h>
#include <math.h>

#define MAXNORM 0.996f      // (1 - 4e-3) / sqrt(-K)
#define MINV    1e-15f
#define CLIPV   0.99999988f // f32(1 - 1e-7)

typedef _Float16 f16x8 __attribute__((ext_vector_type(8)));
typedef float f32x4 __attribute__((ext_vector_type(4)));

__device__ __forceinline__ float waveReduce(float v) {
#pragma unroll
    for (int off = 32; off; off >>= 1) v += __shfl_down(v, off, 64);
    return v;
}

__device__ __forceinline__ float waveAllSum(float v) {
#pragma unroll
    for (int off = 32; off; off >>= 1) v += __shfl_xor(v, off, 64);
    return v;
}

__device__ __forceinline__ float artanh_clip(float z) {
    z = fminf(z, CLIPV);
    return 0.5f * logf((1.0f + z) / (1.0f - z));
}

// split f32 -> f16 high + f16 low (Ootomo 2-term)
__device__ __forceinline__ void cvt_split8(const float4 a, const float4 b,
                                           f16x8& h, f16x8& l) {
    h[0] = (_Float16)a.x; l[0] = (_Float16)(a.x - (float)h[0]);
    h[1] = (_Float16)a.y; l[1] = (_Float16)(a.y - (float)h[1]);
    h[2] = (_Float16)a.z; l[2] = (_Float16)(a.z - (float)h[2]);
    h[3] = (_Float16)a.w; l[3] = (_Float16)(a.w - (float)h[3]);
    h[4] = (_Float16)b.x; l[4] = (_Float16)(b.x - (float)h[4]);
    h[5] = (_Float16)b.y; l[5] = (_Float16)(b.y - (float)h[5]);
    h[6] = (_Float16)b.z; l[6] = (_Float16)(b.z - (float)h[6]);
    h[7] = (_Float16)b.w; l[7] = (_Float16)(b.w - (float)h[7]);
}

// ---------------- pack W [N][256] f32 -> fragment-ordered f16 h/l pairs ----
// frag slot layout: Wp[(((n>>4)*8 + ks)*2 + hl)*64 + (kc&3)*16 + (n&15)],
// each slot = 8 consecutive k (f16x8). Same (quarter,elem)->k map as A-side.
template <int N>
__global__ __launch_bounds__(256) void pack_w_kernel(const float* __restrict__ W,
                                                     f16x8* __restrict__ Wp) {
    int idx = blockIdx.x * 256 + threadIdx.x;
    if (idx >= N * 32) return;
    int n = idx >> 5, kc = idx & 31;
    const float4* p = reinterpret_cast<const float4*>(W + (size_t)n * 256 + kc * 8);
    f16x8 h, l;
    cvt_split8(p[0], p[1], h, l);
    int base = (((n >> 4) * 8 + (kc >> 2)) * 2) * 64 + (kc & 3) * 16 + (n & 15);
    Wp[base] = h;
    Wp[base + 64] = l;   // hl stride = 64 slots
}

// ---------------- kb = expmap0(b); also y2 = ||kb||^2 ----------------
template <int D>
__global__ __launch_bounds__(D) void kb_kernel(const float* __restrict__ b,
                                               float* __restrict__ kb,
                                               float* __restrict__ y2out) {
    constexpr int NW = D / 64;
    __shared__ float red[NW];
    int j = threadIdx.x;
    float u = b[j];
    float ss = waveReduce(u * u);
    if ((j & 63) == 0) red[j >> 6] = ss;
    __syncthreads();
    float tot = 0;
#pragma unroll
    for (int w = 0; w < NW; ++w) tot += red[w];
    float un = fmaxf(sqrtf(tot), MINV);
    float t = tanhf(un);
    float s = t / un;
    if (t > MAXNORM) s *= MAXNORM / t;
    float v = u * s;
    kb[j] = v;
    float ss2 = waveReduce(v * v);
    __syncthreads();
    if ((j & 63) == 0) red[j >> 6] = ss2;
    __syncthreads();
    if (j == 0) {
        float t2 = 0;
        for (int w = 0; w < NW; ++w) t2 += red[w];
        y2out[0] = t2;
    }
}

// ---------------- MFMA split-f16 layer: mv = X@W^T (3-product) ;
// optional fused expmap0 on input ; mobius post-scale ; mobius_add(kb) ;
// logmap0 -> XT.  Block: 256 thr (4 waves), 32 rows, full N width. --------
template <int N, bool FUSE_EXP>
__global__ __launch_bounds__(256) void mfma_layer_kernel(
        const float* __restrict__ X,   // [n][256] raw x (FUSE_EXP) or h
        const f16x8* __restrict__ Wp,  // packed fragments
        const float* __restrict__ kb,  // [N]
        const float* __restrict__ y2p, // scalar ||kb||^2
        float* __restrict__ XT,        // [n][N]
        int n) {
    constexpr int BM = 32, KS = 8, NF = N / 64;  // n-frags per wave
    __shared__ f16x8 sAB[2048];   // 32 slabs x 64 slots = 32 KB
    __shared__ float sXS[BM];
    __shared__ float sS[BM][4];
    float* sV = reinterpret_cast<float*>(sAB);  // [BM][N] overlay post-MFMA

    const int t = threadIdx.x;
    const int wave = t >> 6, lane = t & 63;
    const size_t r0 = (size_t)blockIdx.x * BM;

    if (t < BM) sXS[t] = 0.0f;
    __syncthreads();

    // ---- stage A (f32 -> f16 h/l fragments) + row sumsq ----
    const int arow = t & 31;        // fixed row per thread
    const int kc0 = t >> 5;         // 0..7
    const bool valid = (r0 + arow) < (size_t)n;
    const float* xrow = X + (r0 + arow) * 256;
    float part = 0.0f;
#pragma unroll
    for (int i = 0; i < 4; ++i) {
        const int kc = i * 8 + kc0;
        float4 a = make_float4(0.f, 0.f, 0.f, 0.f);
        float4 b = make_float4(0.f, 0.f, 0.f, 0.f);
        if (valid) {
            a = *reinterpret_cast<const float4*>(xrow + kc * 8);
            b = *reinterpret_cast<const float4*>(xrow + kc * 8 + 4);
        }
        part += a.x * a.x + a.y * a.y + a.z * a.z + a.w * a.w +
                b.x * b.x + b.y * b.y + b.z * b.z + b.w * b.w;
        f16x8 h, l;
        cvt_split8(a, b, h, l);
        const int slab = (kc >> 2) * 4 + (arow >> 4);  // (ks*2+hl)*2+mf, hl=0
        const int slot = (kc & 3) * 16 + (arow & 15);
        sAB[slab * 64 + slot] = h;
        sAB[(slab + 2) * 64 + slot] = l;               // hl=1
    }
    atomicAdd(&sXS[arow], part);
    __syncthreads();

    // ---- MFMA main loop ----
    f32x4 acc[2][NF];
#pragma unroll
    for (int mf = 0; mf < 2; ++mf)
#pragma unroll
        for (int nf = 0; nf < NF; ++nf) acc[mf][nf] = (f32x4){0.f, 0.f, 0.f, 0.f};

    const int nf0 = wave * NF;
#pragma unroll
    for (int ks = 0; ks < KS; ++ks) {
        const f16x8 ah0 = sAB[(ks * 4 + 0) * 64 + lane];
        const f16x8 ah1 = sAB[(ks * 4 + 1) * 64 + lane];
        const f16x8 al0 = sAB[(ks * 4 + 2) * 64 + lane];
        const f16x8 al1 = sAB[(ks * 4 + 3) * 64 + lane];
#pragma unroll
        for (int nf = 0; nf < NF; ++nf) {
            const f16x8 bh = Wp[(((nf0 + nf) * 8 + ks) * 2 + 0) * 64 + lane];
            const f16x8 bl = Wp[(((nf0 + nf) * 8 + ks) * 2 + 1) * 64 + lane];
            acc[0][nf] = __builtin_amdgcn_mfma_f32_16x16x32_f16(ah0, bh, acc[0][nf], 0, 0, 0);
            acc[1][nf] = __builtin_amdgcn_mfma_f32_16x16x32_f16(ah1, bh, acc[1][nf], 0, 0, 0);
            acc[0][nf] = __builtin_amdgcn_mfma_f32_16x16x32_f16(ah0, bl, acc[0][nf], 0, 0, 0);
            acc[1][nf] = __builtin_amdgcn_mfma_f32_16x16x32_f16(ah1, bl, acc[1][nf], 0, 0, 0);
            acc[0][nf] = __builtin_amdgcn_mfma_f32_16x16x32_f16(al0, bh, acc[0][nf], 0, 0, 0);
            acc[1][nf] = __builtin_amdgcn_mfma_f32_16x16x32_f16(al1, bh, acc[1][nf], 0, 0, 0);
        }
    }
    __syncthreads();   // done reading sAB; overlay as sV

    // ---- spill mv to LDS (C layout: col=lane&15, row=(lane>>4)*4+reg) ----
    {
        const int crow = (lane >> 4) * 4;
        const int ccol = wave * (N / 4) + (lane & 15);
#pragma unroll
        for (int mf = 0; mf < 2; ++mf)
#pragma unroll
            for (int nf = 0; nf < NF; ++nf)
#pragma unroll
                for (int rg = 0; rg < 4; ++rg)
                    sV[(mf * 16 + crow + rg) * N + ccol + nf * 16] = acc[mf][nf][rg];
    }
    __syncthreads();

    // ---- epilogue: per-row hyperbolic maps (8 rows per wave) ----
    const float y2 = *y2p;
#pragma unroll
    for (int q = 0; q < 8; ++q) {
        const int r = wave * 8 + q;
        float ms = 0.f, xy = 0.f;
        for (int c = lane; c < N; c += 64) {
            float m = sV[r * N + c];
            ms += m * m;
            xy += m * kb[c];
        }
        ms = waveReduce(ms);
        xy = waveReduce(xy);
        if (lane == 0) {
            const float xs = sXS[r];
            const float un = fmaxf(sqrtf(xs), MINV);
            float xn0;
            if (FUSE_EXP) {
                float tt = tanhf(un);
                float alpha = tt / un;
                if (tt > MAXNORM) alpha = MAXNORM / un;
                xn0 = alpha * un;   // ||expmap0(x)||
            } else {
                xn0 = un;
            }
            const float mvn_r = fmaxf(sqrtf(ms), MINV);
            const float t1 = tanhf(mvn_r / un * artanh_clip(xn0));
            float sC = t1 / mvn_r;
            float rn = t1;
            if (t1 > MAXNORM) { sC = MAXNORM / mvn_r; rn = MAXNORM; }  // project
            const float x2 = rn * rn;
            const float xyr = sC * xy;
            const float ca = 1.0f + 2.0f * xyr + y2;
            const float cb = 1.0f - x2;
            const float den = fmaxf(1.0f + 2.0f * xyr + x2 * y2, MINV);
            sS[r][0] = ca * sC / den;  // coeff on sV
            sS[r][1] = cb / den;       // coeff on kb
        }
    }
    __syncthreads();
#pragma unroll
    for (int q = 0; q < 8; ++q) {
        const int r = wave * 8 + q;
        const float p = sS[r][0], qq = sS[r][1];
        float os = 0.f;
        for (int c = lane; c < N; c += 64) {
            float o = p * sV[r * N + c] + qq * kb[c];
            os += o * o;
        }
        os = waveReduce(os);
        if (lane == 0) {
            float on = fmaxf(sqrtf(os), MINV);
            float s2 = (on > MAXNORM) ? (MAXNORM / on) : 1.0f;  // project
            float yn = fmaxf(on * s2, MINV);
            sS[r][2] = artanh_clip(yn) / yn * s2;               // logmap0
        }
    }
    __syncthreads();
    for (int idx = t; idx < BM * N; idx += 256) {
        const int r = (N == 256) ? (idx >> 8) : (idx >> 7);
        const int c = idx & (N - 1);
        if (r0 + r < (size_t)n)
            XT[(r0 + r) * N + c] = sS[r][2] * (sS[r][0] * sV[idx] + sS[r][1] * kb[c]);
    }
}

// ---------------- CSR build ----------------
__global__ void count_in_kernel(const int* __restrict__ col, int E, int* __restrict__ icnt) {
    int e = blockIdx.x * 256 + threadIdx.x;
    if (e < E) atomicAdd(&icnt[col[e]], 1);
}

// dis = rsqrt(icnt+1); offs/cursor via atomic range assignment (order-free)
__global__ void dis_kernel(const int* __restrict__ icnt, float* __restrict__ dis,
                           int* __restrict__ offs, int* __restrict__ cursor,
                           int* __restrict__ gcnt, int n) {
    int i = blockIdx.x * 256 + threadIdx.x;
    if (i < n) {
        int c = icnt[i];
        dis[i] = rsqrtf((float)(c + 1));
        int p = atomicAdd(gcnt, c);
        offs[i] = p;
        cursor[i] = p;
    }
}

__global__ void csr_scatter(const int* __restrict__ row, const int* __restrict__ col,
                            const float* __restrict__ dis, int E,
                            int* __restrict__ cursor, int* __restrict__ csr_src,
                            float* __restrict__ csr_w) {
    int e = blockIdx.x * 256 + threadIdx.x;
    if (e >= E) return;
    int r = row[e], c = col[e];
    int p = atomicAdd(&cursor[c], 1);
    csr_src[p] = r;
    csr_w[p] = dis[r] * dis[c];
}

// ---------------- gather + expmap0: one wave per node ----------------
template <int D>
__global__ __launch_bounds__(256) void gather_expmap_kernel(
        const float* __restrict__ xt, const float* __restrict__ dis,
        const int* __restrict__ offs, const int* __restrict__ icnt,
        const int* __restrict__ csr_src, const float* __restrict__ csr_w,
        int n, float* __restrict__ out) {
    constexpr int PER = D / 64;  // 4 (D=256) or 2 (D=128)
    int node = blockIdx.x * 4 + (threadIdx.x >> 6);
    if (node >= n) return;
    int lid = threadIdx.x & 63;

    float acc[PER];
    float wc = dis[node];
    float wself = wc * wc;
    {
        const float* sp = xt + (size_t)node * D + lid * PER;
        if constexpr (PER == 4) {
            const float4 v = *reinterpret_cast<const float4*>(sp);
            acc[0] = wself * v.x; acc[1] = wself * v.y;
            acc[2] = wself * v.z; acc[3] = wself * v.w;
        } else {
            const float2 v = *reinterpret_cast<const float2*>(sp);
            acc[0] = wself * v.x; acc[1] = wself * v.y;
        }
    }

    const int s = offs[node];
    const int e = s + icnt[node];
    int p = s;
    for (; p + 1 < e; p += 2) {
        const int r0v = csr_src[p], r1v = csr_src[p + 1];
        const float w0 = csr_w[p], w1 = csr_w[p + 1];
        const float* s0 = xt + (size_t)r0v * D + lid * PER;
        const float* s1 = xt + (size_t)r1v * D + lid * PER;
        if constexpr (PER == 4) {
            const float4 v0 = *reinterpret_cast<const float4*>(s0);
            const float4 v1 = *reinterpret_cast<const float4*>(s1);
            acc[0] = fmaf(w0, v0.x, acc[0]); acc[1] = fmaf(w0, v0.y, acc[1]);
            acc[2] = fmaf(w0, v0.z, acc[2]); acc[3] = fmaf(w0, v0.w, acc[3]);
            acc[0] = fmaf(w1, v1.x, acc[0]); acc[1] = fmaf(w1, v1.y, acc[1]);
            acc[2] = fmaf(w1, v1.z, acc[2]); acc[3] = fmaf(w1, v1.w, acc[3]);
        } else {
            const float2 v0 = *reinterpret_cast<const float2*>(s0);
            const float2 v1 = *reinterpret_cast<const float2*>(s1);
            acc[0] = fmaf(w0, v0.x, acc[0]); acc[1] = fmaf(w0, v0.y, acc[1]);
            acc[0] = fmaf(w1, v1.x, acc[0]); acc[1] = fmaf(w1, v1.y, acc[1]);
        }
    }
    if (p < e) {
        const int rv = csr_src[p];
        const float w = csr_w[p];
        const float* sp = xt + (size_t)rv * D + lid * PER;
        if constexpr (PER == 4) {
            const float4 v = *reinterpret_cast<const float4*>(sp);
            acc[0] = fmaf(w, v.x, acc[0]); acc[1] = fmaf(w, v.y, acc[1]);
            acc[2] = fmaf(w, v.z, acc[2]); acc[3] = fmaf(w, v.w, acc[3]);
        } else {
            const float2 v = *reinterpret_cast<const float2*>(sp);
            acc[0] = fmaf(w, v.x, acc[0]); acc[1] = fmaf(w, v.y, acc[1]);
        }
    }

    // expmap0 in-register
    float ss = 0;
#pragma unroll
    for (int q = 0; q < PER; ++q) ss += acc[q] * acc[q];
    ss = waveAllSum(ss);
    float un = fmaxf(sqrtf(ss), MINV);
    float t = tanhf(un);
    float sc = t / un;
    if (t > MAXNORM) sc *= MAXNORM / t;

    float* op = out + (size_t)node * D + lid * PER;
    if constexpr (PER == 4) {
        float4 o;
        o.x = sc * acc[0]; o.y = sc * acc[1]; o.z = sc * acc[2]; o.w = sc * acc[3];
        *reinterpret_cast<float4*>(op) = o;
    } else {
        float2 o;
        o.x = sc * acc[0]; o.y = sc * acc[1];
        *reinterpret_cast<float2*>(op) = o;
    }
}

extern "C" void kernel_launch(void* const* d_in, const int* in_sizes, int n_in,
                              void* d_out, int out_size, void* d_ws, size_t ws_size,
                              hipStream_t stream) {
    const float* x  = (const float*)d_in[0];
    const float* W1 = (const float*)d_in[1];
    const float* b1 = (const float*)d_in[2];
    const float* W2 = (const float*)d_in[3];
    const float* b2 = (const float*)d_in[4];
    const int*   ei = (const int*)d_in[5];

    const int N = in_sizes[0] / 256;
    const int E = in_sizes[5] / 2;
    const int* row = ei;
    const int* col = ei + E;

    float* ws = (float*)d_ws;
    size_t off = 0;
    float* A    = ws + off; off += (size_t)N * 256;
    float* C    = ws + off; off += (size_t)N * 256;
    f16x8* Wp1  = (f16x8*)(ws + off); off += 256 * 256;  // 256 KB
    f16x8* Wp2  = (f16x8*)(ws + off); off += 128 * 256;  // 128 KB
    float* kb1  = ws + off; off += 256;
    float* kb2  = ws + off; off += 128;
    float* y2s  = ws + off; off += 4;
    float* dis  = ws + off; off += N;
    int*  icnt  = (int*)(ws + off); off += N;
    int*  gcnt  = (int*)(ws + off); off += 4;
    int*  offs  = (int*)(ws + off); off += N;
    int*  cursor= (int*)(ws + off); off += N;
    int*  csrs  = (int*)(ws + off); off += E;
    float* csrw = ws + off; off += E;

    // weight prep + bias maps
    pack_w_kernel<256><<<(256 * 32 + 255) / 256, 256, 0, stream>>>(W1, Wp1);
    pack_w_kernel<128><<<(128 * 32 + 255) / 256, 256, 0, stream>>>(W2, Wp2);
    kb_kernel<256><<<1, 256, 0, stream>>>(b1, kb1, y2s);
    kb_kernel<128><<<1, 128, 0, stream>>>(b2, kb2, y2s + 1);

    // CSR build: in-degree -> atomic range assignment -> scatter
    hipMemsetAsync(icnt, 0, (size_t)N * sizeof(int), stream);
    hipMemsetAsync(gcnt, 0, sizeof(int), stream);
    count_in_kernel<<<(E + 255) / 256, 256, 0, stream>>>(col, E, icnt);
    dis_kernel<<<(N + 255) / 256, 256, 0, stream>>>(icnt, dis, offs, cursor, gcnt, N);
    csr_scatter<<<(E + 255) / 256, 256, 0, stream>>>(row, col, dis, E, cursor, csrs, csrw);

    const int nblk = (N + 31) / 32;
    // ----- layer 1 (N=256, fused expmap0 on raw x) -----
    mfma_layer_kernel<256, true><<<nblk, 256, 0, stream>>>(x, Wp1, kb1, y2s, C, N);
    gather_expmap_kernel<256><<<(N + 3) / 4, 256, 0, stream>>>(C, dis, offs, icnt, csrs, csrw, N, A);

    // ----- layer 2 (N=128) -----
    mfma_layer_kernel<128, false><<<nblk, 256, 0, stream>>>(A, Wp2, kb2, y2s + 1, C, N);
    gather_expmap_kernel<128><<<(N + 3) / 4, 256, 0, stream>>>(C, dis, offs, icnt, csrs, csrw, N, (float*)d_out);
}

// Round 4
// 347.036 us; speedup vs baseline: 11.3214x; 1.2143x over previous
//
#include <hip/hip_runtime.h>
#include <math.h>

#define MAXNORM 0.996f      // (1 - 4e-3) / sqrt(-K)
#define MINV    1e-15f
#define CLIPV   0.99999988f // f32(1 - 1e-7)

typedef _Float16 f16x8 __attribute__((ext_vector_type(8)));
typedef _Float16 h16x4 __attribute__((ext_vector_type(4)));
typedef _Float16 h16x2 __attribute__((ext_vector_type(2)));
typedef float f32x4 __attribute__((ext_vector_type(4)));

__device__ __forceinline__ float waveReduce(float v) {
#pragma unroll
    for (int off = 32; off; off >>= 1) v += __shfl_down(v, off, 64);
    return v;
}

__device__ __forceinline__ float waveAllSum(float v) {
#pragma unroll
    for (int off = 32; off; off >>= 1) v += __shfl_xor(v, off, 64);
    return v;
}

__device__ __forceinline__ float artanh_clip(float z) {
    z = fminf(z, CLIPV);
    return 0.5f * logf((1.0f + z) / (1.0f - z));
}

// split f32 -> f16 high + f16 low (Ootomo 2-term)
__device__ __forceinline__ void cvt_split8(const float4 a, const float4 b,
                                           f16x8& h, f16x8& l) {
    h[0] = (_Float16)a.x; l[0] = (_Float16)(a.x - (float)h[0]);
    h[1] = (_Float16)a.y; l[1] = (_Float16)(a.y - (float)h[1]);
    h[2] = (_Float16)a.z; l[2] = (_Float16)(a.z - (float)h[2]);
    h[3] = (_Float16)a.w; l[3] = (_Float16)(a.w - (float)h[3]);
    h[4] = (_Float16)b.x; l[4] = (_Float16)(b.x - (float)h[4]);
    h[5] = (_Float16)b.y; l[5] = (_Float16)(b.y - (float)h[5]);
    h[6] = (_Float16)b.z; l[6] = (_Float16)(b.z - (float)h[6]);
    h[7] = (_Float16)b.w; l[7] = (_Float16)(b.w - (float)h[7]);
}

// ---------------- pack W1 [256][256] + W2 [128][256] -> fragment order ----
// slot layout: Wp[(((n>>4)*8 + ks)*2 + hl)*64 + (kc&3)*16 + (n&15)]
__global__ __launch_bounds__(256) void pack_w_both(const float* __restrict__ W1,
                                                   f16x8* __restrict__ Wp1,
                                                   const float* __restrict__ W2,
                                                   f16x8* __restrict__ Wp2) {
    int idx = blockIdx.x * 256 + threadIdx.x;
    const float* W;
    f16x8* Wp;
    int n, kc;
    if (idx < 256 * 32) {
        W = W1; Wp = Wp1; n = idx >> 5; kc = idx & 31;
    } else {
        idx -= 256 * 32;
        if (idx >= 128 * 32) return;
        W = W2; Wp = Wp2; n = idx >> 5; kc = idx & 31;
    }
    const float4* p = reinterpret_cast<const float4*>(W + (size_t)n * 256 + kc * 8);
    f16x8 h, l;
    cvt_split8(p[0], p[1], h, l);
    int base = (((n >> 4) * 8 + (kc >> 2)) * 2) * 64 + (kc & 3) * 16 + (n & 15);
    Wp[base] = h;
    Wp[base + 64] = l;   // hl stride = 64 slots
}

// ---------------- kb = expmap0(b); y2 = ||kb||^2 (block 0: b1, 1: b2) ----
__global__ __launch_bounds__(256) void kb_both(const float* __restrict__ b1,
                                               float* __restrict__ kb1,
                                               const float* __restrict__ b2,
                                               float* __restrict__ kb2,
                                               float* __restrict__ y2s) {
    const int D = (blockIdx.x == 0) ? 256 : 128;
    const float* b = (blockIdx.x == 0) ? b1 : b2;
    float* kb = (blockIdx.x == 0) ? kb1 : kb2;
    float* y2o = y2s + blockIdx.x;
    __shared__ float red[4];
    int j = threadIdx.x;
    float u = (j < D) ? b[j] : 0.0f;
    float ss = waveReduce(u * u);
    if ((j & 63) == 0) red[j >> 6] = ss;
    __syncthreads();
    float tot = red[0] + red[1] + red[2] + red[3];
    float un = fmaxf(sqrtf(tot), MINV);
    float t = tanhf(un);
    float s = t / un;
    if (t > MAXNORM) s *= MAXNORM / t;
    float v = u * s;
    if (j < D) kb[j] = v;
    float ss2 = waveReduce(v * v);
    __syncthreads();
    if ((j & 63) == 0) red[j >> 6] = ss2;
    __syncthreads();
    if (j == 0) y2o[0] = red[0] + red[1] + red[2] + red[3];
}

// ---------------- MFMA split-f16 layer -> f16 XT ----------------
template <int N, bool FUSE_EXP>
__global__ __launch_bounds__(256) void mfma_layer_kernel(
        const float* __restrict__ X,   // [n][256] raw x (FUSE_EXP) or h
        const f16x8* __restrict__ Wp,  // packed fragments
        const float* __restrict__ kb,  // [N]
        const float* __restrict__ y2p, // scalar ||kb||^2
        _Float16* __restrict__ XT,     // [n][N] f16
        int n) {
    constexpr int BM = 32, KS = 8, NF = N / 64;  // n-frags per wave
    __shared__ f16x8 sAB[2048];   // 32 slabs x 64 slots = 32 KB
    __shared__ float sXS[BM];
    __shared__ float sS[BM][4];
    float* sV = reinterpret_cast<float*>(sAB);  // [BM][N] overlay post-MFMA

    const int t = threadIdx.x;
    const int wave = t >> 6, lane = t & 63;
    const size_t r0 = (size_t)blockIdx.x * BM;

    if (t < BM) sXS[t] = 0.0f;
    __syncthreads();

    // ---- stage A (f32 -> f16 h/l fragments) + row sumsq ----
    const int arow = t & 31;        // fixed row per thread
    const int kc0 = t >> 5;         // 0..7
    const bool valid = (r0 + arow) < (size_t)n;
    const float* xrow = X + (r0 + arow) * 256;
    float part = 0.0f;
#pragma unroll
    for (int i = 0; i < 4; ++i) {
        const int kc = i * 8 + kc0;
        float4 a = make_float4(0.f, 0.f, 0.f, 0.f);
        float4 b = make_float4(0.f, 0.f, 0.f, 0.f);
        if (valid) {
            a = *reinterpret_cast<const float4*>(xrow + kc * 8);
            b = *reinterpret_cast<const float4*>(xrow + kc * 8 + 4);
        }
        part += a.x * a.x + a.y * a.y + a.z * a.z + a.w * a.w +
                b.x * b.x + b.y * b.y + b.z * b.z + b.w * b.w;
        f16x8 h, l;
        cvt_split8(a, b, h, l);
        const int slab = (kc >> 2) * 4 + (arow >> 4);
        const int slot = (kc & 3) * 16 + (arow & 15);
        sAB[slab * 64 + slot] = h;
        sAB[(slab + 2) * 64 + slot] = l;
    }
    atomicAdd(&sXS[arow], part);
    __syncthreads();

    // ---- MFMA main loop ----
    f32x4 acc[2][NF];
#pragma unroll
    for (int mf = 0; mf < 2; ++mf)
#pragma unroll
        for (int nf = 0; nf < NF; ++nf) acc[mf][nf] = (f32x4){0.f, 0.f, 0.f, 0.f};

    const int nf0 = wave * NF;
#pragma unroll
    for (int ks = 0; ks < KS; ++ks) {
        const f16x8 ah0 = sAB[(ks * 4 + 0) * 64 + lane];
        const f16x8 ah1 = sAB[(ks * 4 + 1) * 64 + lane];
        const f16x8 al0 = sAB[(ks * 4 + 2) * 64 + lane];
        const f16x8 al1 = sAB[(ks * 4 + 3) * 64 + lane];
#pragma unroll
        for (int nf = 0; nf < NF; ++nf) {
            const f16x8 bh = Wp[(((nf0 + nf) * 8 + ks) * 2 + 0) * 64 + lane];
            const f16x8 bl = Wp[(((nf0 + nf) * 8 + ks) * 2 + 1) * 64 + lane];
            acc[0][nf] = __builtin_amdgcn_mfma_f32_16x16x32_f16(ah0, bh, acc[0][nf], 0, 0, 0);
            acc[1][nf] = __builtin_amdgcn_mfma_f32_16x16x32_f16(ah1, bh, acc[1][nf], 0, 0, 0);
            acc[0][nf] = __builtin_amdgcn_mfma_f32_16x16x32_f16(ah0, bl, acc[0][nf], 0, 0, 0);
            acc[1][nf] = __builtin_amdgcn_mfma_f32_16x16x32_f16(ah1, bl, acc[1][nf], 0, 0, 0);
            acc[0][nf] = __builtin_amdgcn_mfma_f32_16x16x32_f16(al0, bh, acc[0][nf], 0, 0, 0);
            acc[1][nf] = __builtin_amdgcn_mfma_f32_16x16x32_f16(al1, bh, acc[1][nf], 0, 0, 0);
        }
    }
    __syncthreads();   // done reading sAB; overlay as sV

    // ---- spill mv to LDS (C layout: col=lane&15, row=(lane>>4)*4+reg) ----
    {
        const int crow = (lane >> 4) * 4;
        const int ccol = wave * (N / 4) + (lane & 15);
#pragma unroll
        for (int mf = 0; mf < 2; ++mf)
#pragma unroll
            for (int nf = 0; nf < NF; ++nf)
#pragma unroll
                for (int rg = 0; rg < 4; ++rg)
                    sV[(mf * 16 + crow + rg) * N + ccol + nf * 16] = acc[mf][nf][rg];
    }
    __syncthreads();

    // ---- epilogue: per-row hyperbolic maps (8 rows per wave) ----
    const float y2 = *y2p;
#pragma unroll
    for (int q = 0; q < 8; ++q) {
        const int r = wave * 8 + q;
        float ms = 0.f, xy = 0.f;
        for (int c = lane; c < N; c += 64) {
            float m = sV[r * N + c];
            ms += m * m;
            xy += m * kb[c];
        }
        ms = waveReduce(ms);
        xy = waveReduce(xy);
        if (lane == 0) {
            const float xs = sXS[r];
            const float un = fmaxf(sqrtf(xs), MINV);
            float xn0;
            if (FUSE_EXP) {
                float tt = tanhf(un);
                float alpha = tt / un;
                if (tt > MAXNORM) alpha = MAXNORM / un;
                xn0 = alpha * un;   // ||expmap0(x)||
            } else {
                xn0 = un;
            }
            const float mvn_r = fmaxf(sqrtf(ms), MINV);
            const float t1 = tanhf(mvn_r / un * artanh_clip(xn0));
            float sC = t1 / mvn_r;
            float rn = t1;
            if (t1 > MAXNORM) { sC = MAXNORM / mvn_r; rn = MAXNORM; }  // project
            const float x2 = rn * rn;
            const float xyr = sC * xy;
            const float ca = 1.0f + 2.0f * xyr + y2;
            const float cb = 1.0f - x2;
            const float den = fmaxf(1.0f + 2.0f * xyr + x2 * y2, MINV);
            sS[r][0] = ca * sC / den;  // coeff on sV
            sS[r][1] = cb / den;       // coeff on kb
        }
    }
    __syncthreads();
#pragma unroll
    for (int q = 0; q < 8; ++q) {
        const int r = wave * 8 + q;
        const float p = sS[r][0], qq = sS[r][1];
        float os = 0.f;
        for (int c = lane; c < N; c += 64) {
            float o = p * sV[r * N + c] + qq * kb[c];
            os += o * o;
        }
        os = waveReduce(os);
        if (lane == 0) {
            float on = fmaxf(sqrtf(os), MINV);
            float s2 = (on > MAXNORM) ? (MAXNORM / on) : 1.0f;  // project
            float yn = fmaxf(on * s2, MINV);
            sS[r][2] = artanh_clip(yn) / yn * s2;               // logmap0
        }
    }
    __syncthreads();
    for (int idx = t; idx < BM * N; idx += 256) {
        const int r = (N == 256) ? (idx >> 8) : (idx >> 7);
        const int c = idx & (N - 1);
        if (r0 + r < (size_t)n)
            XT[(r0 + r) * N + c] =
                (_Float16)(sS[r][2] * (sS[r][0] * sV[idx] + sS[r][1] * kb[c]));
    }
}

// ---------------- CSR build ----------------
__global__ void count_in_kernel(const int* __restrict__ col, int E, int* __restrict__ icnt) {
    int e = blockIdx.x * 256 + threadIdx.x;
    if (e < E) atomicAdd(&icnt[col[e]], 1);
}

// dis = rsqrt(icnt+1); offs/cursor via atomic range assignment (order-free)
__global__ void dis_kernel(const int* __restrict__ icnt, float* __restrict__ dis,
                           int* __restrict__ offs, int* __restrict__ cursor,
                           int* __restrict__ gcnt, int n) {
    int i = blockIdx.x * 256 + threadIdx.x;
    if (i < n) {
        int c = icnt[i];
        dis[i] = rsqrtf((float)(c + 1));
        int p = atomicAdd(gcnt, c);
        offs[i] = p;
        cursor[i] = p;
    }
}

__global__ void csr_scatter(const int* __restrict__ row, const int* __restrict__ col,
                            const float* __restrict__ dis, int E,
                            int* __restrict__ cursor, int* __restrict__ csr_src,
                            float* __restrict__ csr_w) {
    int e = blockIdx.x * 256 + threadIdx.x;
    if (e >= E) return;
    int r = row[e], c = col[e];
    int p = atomicAdd(&cursor[c], 1);
    csr_src[p] = r;
    csr_w[p] = dis[r] * dis[c];
}

// ---------------- gather (f16 rows) + expmap0: one wave per node ----------
template <int D>
__global__ __launch_bounds__(256) void gather_expmap_kernel(
        const _Float16* __restrict__ xt, const float* __restrict__ dis,
        const int* __restrict__ offs, const int* __restrict__ icnt,
        const int* __restrict__ csr_src, const float* __restrict__ csr_w,
        int n, float* __restrict__ out) {
    constexpr int PER = D / 64;  // 4 (D=256) or 2 (D=128)
    int node = blockIdx.x * 4 + (threadIdx.x >> 6);
    if (node >= n) return;
    int lid = threadIdx.x & 63;
    const int loff = lid * PER;

    float acc[PER];
    float wc = dis[node];
    float wself = wc * wc;
    if constexpr (PER == 4) {
        const h16x4 v = *reinterpret_cast<const h16x4*>(xt + (size_t)node * D + loff);
#pragma unroll
        for (int q = 0; q < 4; ++q) acc[q] = wself * (float)v[q];
    } else {
        const h16x2 v = *reinterpret_cast<const h16x2*>(xt + (size_t)node * D + loff);
#pragma unroll
        for (int q = 0; q < 2; ++q) acc[q] = wself * (float)v[q];
    }

    const int s = offs[node];
    const int e = s + icnt[node];
    int p = s;
    // 4-wide: issue all index+row loads before accumulating (MLP)
    for (; p + 4 <= e; p += 4) {
        const int ia = csr_src[p], ib = csr_src[p + 1], ic = csr_src[p + 2], id = csr_src[p + 3];
        const float wa = csr_w[p], wb = csr_w[p + 1], wcc = csr_w[p + 2], wd = csr_w[p + 3];
        if constexpr (PER == 4) {
            const h16x4 va = *reinterpret_cast<const h16x4*>(xt + (size_t)ia * D + loff);
            const h16x4 vb = *reinterpret_cast<const h16x4*>(xt + (size_t)ib * D + loff);
            const h16x4 vc = *reinterpret_cast<const h16x4*>(xt + (size_t)ic * D + loff);
            const h16x4 vd = *reinterpret_cast<const h16x4*>(xt + (size_t)id * D + loff);
#pragma unroll
            for (int q = 0; q < 4; ++q) {
                acc[q] = fmaf(wa, (float)va[q], acc[q]);
                acc[q] = fmaf(wb, (float)vb[q], acc[q]);
                acc[q] = fmaf(wcc, (float)vc[q], acc[q]);
                acc[q] = fmaf(wd, (float)vd[q], acc[q]);
            }
        } else {
            const h16x2 va = *reinterpret_cast<const h16x2*>(xt + (size_t)ia * D + loff);
            const h16x2 vb = *reinterpret_cast<const h16x2*>(xt + (size_t)ib * D + loff);
            const h16x2 vc = *reinterpret_cast<const h16x2*>(xt + (size_t)ic * D + loff);
            const h16x2 vd = *reinterpret_cast<const h16x2*>(xt + (size_t)id * D + loff);
#pragma unroll
            for (int q = 0; q < 2; ++q) {
                acc[q] = fmaf(wa, (float)va[q], acc[q]);
                acc[q] = fmaf(wb, (float)vb[q], acc[q]);
                acc[q] = fmaf(wcc, (float)vc[q], acc[q]);
                acc[q] = fmaf(wd, (float)vd[q], acc[q]);
            }
        }
    }
    for (; p < e; ++p) {
        const int rv = csr_src[p];
        const float w = csr_w[p];
        if constexpr (PER == 4) {
            const h16x4 v = *reinterpret_cast<const h16x4*>(xt + (size_t)rv * D + loff);
#pragma unroll
            for (int q = 0; q < 4; ++q) acc[q] = fmaf(w, (float)v[q], acc[q]);
        } else {
            const h16x2 v = *reinterpret_cast<const h16x2*>(xt + (size_t)rv * D + loff);
#pragma unroll
            for (int q = 0; q < 2; ++q) acc[q] = fmaf(w, (float)v[q], acc[q]);
        }
    }

    // expmap0 in-register
    float ss = 0;
#pragma unroll
    for (int q = 0; q < PER; ++q) ss += acc[q] * acc[q];
    ss = waveAllSum(ss);
    float un = fmaxf(sqrtf(ss), MINV);
    float t = tanhf(un);
    float sc = t / un;
    if (t > MAXNORM) sc *= MAXNORM / t;

    float* op = out + (size_t)node * D + loff;
    if constexpr (PER == 4) {
        float4 o;
        o.x = sc * acc[0]; o.y = sc * acc[1]; o.z = sc * acc[2]; o.w = sc * acc[3];
        *reinterpret_cast<float4*>(op) = o;
    } else {
        float2 o;
        o.x = sc * acc[0]; o.y = sc * acc[1];
        *reinterpret_cast<float2*>(op) = o;
    }
}

extern "C" void kernel_launch(void* const* d_in, const int* in_sizes, int n_in,
                              void* d_out, int out_size, void* d_ws, size_t ws_size,
                              hipStream_t stream) {
    const float* x  = (const float*)d_in[0];
    const float* W1 = (const float*)d_in[1];
    const float* b1 = (const float*)d_in[2];
    const float* W2 = (const float*)d_in[3];
    const float* b2 = (const float*)d_in[4];
    const int*   ei = (const int*)d_in[5];

    const int N = in_sizes[0] / 256;
    const int E = in_sizes[5] / 2;
    const int* row = ei;
    const int* col = ei + E;

    float* ws = (float*)d_ws;
    size_t off = 0;
    float* A      = ws + off; off += (size_t)N * 256;            // f32 h buffer
    _Float16* C   = (_Float16*)(ws + off); off += (size_t)N * 128; // f16 xt
    f16x8* Wp1    = (f16x8*)(ws + off); off += 256 * 256;
    f16x8* Wp2    = (f16x8*)(ws + off); off += 128 * 256;
    float* kb1    = ws + off; off += 256;
    float* kb2    = ws + off; off += 128;
    float* y2s    = ws + off; off += 4;
    float* dis    = ws + off; off += N;
    int*  icnt    = (int*)(ws + off); off += N;
    int*  gcnt    = (int*)(ws + off); off += 4;
    int*  offs    = (int*)(ws + off); off += N;
    int*  cursor  = (int*)(ws + off); off += N;
    int*  csrs    = (int*)(ws + off); off += E;
    float* csrw   = ws + off; off += E;

    // weight prep + bias maps (fused launches)
    pack_w_both<<<(384 * 32 + 255) / 256, 256, 0, stream>>>(W1, Wp1, W2, Wp2);
    kb_both<<<2, 256, 0, stream>>>(b1, kb1, b2, kb2, y2s);

    // CSR build: in-degree -> atomic range assignment -> scatter
    hipMemsetAsync(icnt, 0, (size_t)(N + 4) * sizeof(int), stream);  // icnt + gcnt
    count_in_kernel<<<(E + 255) / 256, 256, 0, stream>>>(col, E, icnt);
    dis_kernel<<<(N + 255) / 256, 256, 0, stream>>>(icnt, dis, offs, cursor, gcnt, N);
    csr_scatter<<<(E + 255) / 256, 256, 0, stream>>>(row, col, dis, E, cursor, csrs, csrw);

    const int nblk = (N + 31) / 32;
    // ----- layer 1 (N=256, fused expmap0 on raw x) -----
    mfma_layer_kernel<256, true><<<nblk, 256, 0, stream>>>(x, Wp1, kb1, y2s, C, N);
    gather_expmap_kernel<256><<<(N + 3) / 4, 256, 0, stream>>>(C, dis, offs, icnt, csrs, csrw, N, A);

    // ----- layer 2 (N=128) -----
    mfma_layer_kernel<128, false><<<nblk, 256, 0, stream>>>(A, Wp2, kb2, y2s + 1, C, N);
    gather_expmap_kernel<128><<<(N + 3) / 4, 256, 0, stream>>>(C, dis, offs, icnt, csrs, csrw, N, (float*)d_out);
}

// Round 5
// 290.318 us; speedup vs baseline: 13.5332x; 1.1954x over previous
//
#include <hip/hip_runtime.h>
#include <math.h>

#define MAXNORM 0.996f      // (1 - 4e-3) / sqrt(-K)
#define MINV    1e-15f
#define CLIPV   0.99999988f // f32(1 - 1e-7)

typedef _Float16 f16x8 __attribute__((ext_vector_type(8)));
typedef _Float16 h16x4 __attribute__((ext_vector_type(4)));
typedef _Float16 h16x2 __attribute__((ext_vector_type(2)));
typedef float f32x4 __attribute__((ext_vector_type(4)));

__device__ __forceinline__ float waveReduce(float v) {
#pragma unroll
    for (int off = 32; off; off >>= 1) v += __shfl_down(v, off, 64);
    return v;
}

__device__ __forceinline__ float waveAllSum(float v) {
#pragma unroll
    for (int off = 32; off; off >>= 1) v += __shfl_xor(v, off, 64);
    return v;
}

__device__ __forceinline__ float artanh_clip(float z) {
    z = fminf(z, CLIPV);
    return 0.5f * logf((1.0f + z) / (1.0f - z));
}

// split f32 -> f16 high + f16 low (Ootomo 2-term)
__device__ __forceinline__ void cvt_split8(const float4 a, const float4 b,
                                           f16x8& h, f16x8& l) {
    h[0] = (_Float16)a.x; l[0] = (_Float16)(a.x - (float)h[0]);
    h[1] = (_Float16)a.y; l[1] = (_Float16)(a.y - (float)h[1]);
    h[2] = (_Float16)a.z; l[2] = (_Float16)(a.z - (float)h[2]);
    h[3] = (_Float16)a.w; l[3] = (_Float16)(a.w - (float)h[3]);
    h[4] = (_Float16)b.x; l[4] = (_Float16)(b.x - (float)h[4]);
    h[5] = (_Float16)b.y; l[5] = (_Float16)(b.y - (float)h[5]);
    h[6] = (_Float16)b.z; l[6] = (_Float16)(b.z - (float)h[6]);
    h[7] = (_Float16)b.w; l[7] = (_Float16)(b.w - (float)h[7]);
}

// ---------------- pack W1 [256][256] + W2 [128][256] -> fragment order ----
// slot layout: Wp[(((n>>4)*8 + ks)*2 + hl)*64 + (kc&3)*16 + (n&15)]
__global__ __launch_bounds__(256) void pack_w_both(const float* __restrict__ W1,
                                                   f16x8* __restrict__ Wp1,
                                                   const float* __restrict__ W2,
                                                   f16x8* __restrict__ Wp2) {
    int idx = blockIdx.x * 256 + threadIdx.x;
    const float* W;
    f16x8* Wp;
    int n, kc;
    if (idx < 256 * 32) {
        W = W1; Wp = Wp1; n = idx >> 5; kc = idx & 31;
    } else {
        idx -= 256 * 32;
        if (idx >= 128 * 32) return;
        W = W2; Wp = Wp2; n = idx >> 5; kc = idx & 31;
    }
    const float4* p = reinterpret_cast<const float4*>(W + (size_t)n * 256 + kc * 8);
    f16x8 h, l;
    cvt_split8(p[0], p[1], h, l);
    int base = (((n >> 4) * 8 + (kc >> 2)) * 2) * 64 + (kc & 3) * 16 + (n & 15);
    Wp[base] = h;
    Wp[base + 64] = l;   // hl stride = 64 slots
}

// ---------------- kb = expmap0(b); y2 = ||kb||^2 (block 0: b1, 1: b2) ----
__global__ __launch_bounds__(256) void kb_both(const float* __restrict__ b1,
                                               float* __restrict__ kb1,
                                               const float* __restrict__ b2,
                                               float* __restrict__ kb2,
                                               float* __restrict__ y2s) {
    const int D = (blockIdx.x == 0) ? 256 : 128;
    const float* b = (blockIdx.x == 0) ? b1 : b2;
    float* kb = (blockIdx.x == 0) ? kb1 : kb2;
    float* y2o = y2s + blockIdx.x;
    __shared__ float red[4];
    int j = threadIdx.x;
    float u = (j < D) ? b[j] : 0.0f;
    float ss = waveReduce(u * u);
    if ((j & 63) == 0) red[j >> 6] = ss;
    __syncthreads();
    float tot = red[0] + red[1] + red[2] + red[3];
    float un = fmaxf(sqrtf(tot), MINV);
    float t = tanhf(un);
    float s = t / un;
    if (t > MAXNORM) s *= MAXNORM / t;
    float v = u * s;
    if (j < D) kb[j] = v;
    float ss2 = waveReduce(v * v);
    __syncthreads();
    if ((j & 63) == 0) red[j >> 6] = ss2;
    __syncthreads();
    if (j == 0) y2o[0] = red[0] + red[1] + red[2] + red[3];
}

// ---------------- MFMA split-f16 layer, register-resident epilogue --------
// acc element (mf, nf, rg) = mv[row][col]:
//   row = mf*16 + (lane>>4)*4 + rg,  col = wave*(N/4) + nf*16 + (lane&15)
template <int N, bool FUSE_EXP>
__global__ __launch_bounds__(256) void mfma_layer_kernel(
        const float* __restrict__ X,   // [n][256] raw x (FUSE_EXP) or h
        const f16x8* __restrict__ Wp,  // packed fragments
        const float* __restrict__ kb,  // [N]
        const float* __restrict__ y2p, // scalar ||kb||^2
        _Float16* __restrict__ XT,     // [n][N] f16
        int n) {
    constexpr int BM = 32, KS = 8, NF = N / 64;  // n-frags per wave
    __shared__ f16x8 sAB[2048];   // 32 slabs x 64 slots = 32 KB
    __shared__ float sXS[BM];
    __shared__ float sRedA[BM][4];
    __shared__ float sRedB[BM][4];
    __shared__ float sS[BM][4];

    const int t = threadIdx.x;
    const int wave = t >> 6, lane = t & 63;
    const size_t r0 = (size_t)blockIdx.x * BM;

    if (t < BM) sXS[t] = 0.0f;
    __syncthreads();

    // ---- stage A (f32 -> f16 h/l fragments) + row sumsq ----
    const int arow = t & 31;        // fixed row per thread
    const int kc0 = t >> 5;         // 0..7
    const bool valid = (r0 + arow) < (size_t)n;
    const float* xrow = X + (r0 + arow) * 256;
    float part = 0.0f;
#pragma unroll
    for (int i = 0; i < 4; ++i) {
        const int kc = i * 8 + kc0;
        float4 a = make_float4(0.f, 0.f, 0.f, 0.f);
        float4 b = make_float4(0.f, 0.f, 0.f, 0.f);
        if (valid) {
            a = *reinterpret_cast<const float4*>(xrow + kc * 8);
            b = *reinterpret_cast<const float4*>(xrow + kc * 8 + 4);
        }
        part += a.x * a.x + a.y * a.y + a.z * a.z + a.w * a.w +
                b.x * b.x + b.y * b.y + b.z * b.z + b.w * b.w;
        f16x8 h, l;
        cvt_split8(a, b, h, l);
        const int slab = (kc >> 2) * 4 + (arow >> 4);
        const int slot = (kc & 3) * 16 + (arow & 15);
        sAB[slab * 64 + slot] = h;
        sAB[(slab + 2) * 64 + slot] = l;
    }
    atomicAdd(&sXS[arow], part);
    __syncthreads();

    // ---- MFMA main loop ----
    f32x4 acc[2][NF];
#pragma unroll
    for (int mf = 0; mf < 2; ++mf)
#pragma unroll
        for (int nf = 0; nf < NF; ++nf) acc[mf][nf] = (f32x4){0.f, 0.f, 0.f, 0.f};

    const int nf0 = wave * NF;
#pragma unroll
    for (int ks = 0; ks < KS; ++ks) {
        const f16x8 ah0 = sAB[(ks * 4 + 0) * 64 + lane];
        const f16x8 ah1 = sAB[(ks * 4 + 1) * 64 + lane];
        const f16x8 al0 = sAB[(ks * 4 + 2) * 64 + lane];
        const f16x8 al1 = sAB[(ks * 4 + 3) * 64 + lane];
#pragma unroll
        for (int nf = 0; nf < NF; ++nf) {
            const f16x8 bh = Wp[(((nf0 + nf) * 8 + ks) * 2 + 0) * 64 + lane];
            const f16x8 bl = Wp[(((nf0 + nf) * 8 + ks) * 2 + 1) * 64 + lane];
            acc[0][nf] = __builtin_amdgcn_mfma_f32_16x16x32_f16(ah0, bh, acc[0][nf], 0, 0, 0);
            acc[1][nf] = __builtin_amdgcn_mfma_f32_16x16x32_f16(ah1, bh, acc[1][nf], 0, 0, 0);
            acc[0][nf] = __builtin_amdgcn_mfma_f32_16x16x32_f16(ah0, bl, acc[0][nf], 0, 0, 0);
            acc[1][nf] = __builtin_amdgcn_mfma_f32_16x16x32_f16(ah1, bl, acc[1][nf], 0, 0, 0);
            acc[0][nf] = __builtin_amdgcn_mfma_f32_16x16x32_f16(al0, bh, acc[0][nf], 0, 0, 0);
            acc[1][nf] = __builtin_amdgcn_mfma_f32_16x16x32_f16(al1, bh, acc[1][nf], 0, 0, 0);
        }
    }

    // ---- hoist kb columns into registers ----
    float kbv[NF];
#pragma unroll
    for (int nf = 0; nf < NF; ++nf)
        kbv[nf] = kb[wave * (N / 4) + nf * 16 + (lane & 15)];

    // ---- phase A: per-row ||mv||^2 and <mv,kb> from registers ----
#pragma unroll
    for (int mf = 0; mf < 2; ++mf)
#pragma unroll
        for (int rg = 0; rg < 4; ++rg) {
            float ms = 0.f, xy = 0.f;
#pragma unroll
            for (int nf = 0; nf < NF; ++nf) {
                const float m = acc[mf][nf][rg];
                ms = fmaf(m, m, ms);
                xy = fmaf(m, kbv[nf], xy);
            }
#pragma unroll
            for (int mask = 1; mask < 16; mask <<= 1) {
                ms += __shfl_xor(ms, mask, 64);
                xy += __shfl_xor(xy, mask, 64);
            }
            if ((lane & 15) == 0) {
                const int row = mf * 16 + (lane >> 4) * 4 + rg;
                sRedA[row][wave] = ms;
                sRedB[row][wave] = xy;
            }
        }
    __syncthreads();

    // ---- 32 parallel per-row coefficient computations ----
    const float y2 = *y2p;
    if (t < BM) {
        const int r = t;
        const float ms = sRedA[r][0] + sRedA[r][1] + sRedA[r][2] + sRedA[r][3];
        const float xy = sRedB[r][0] + sRedB[r][1] + sRedB[r][2] + sRedB[r][3];
        const float xs = sXS[r];
        const float un = fmaxf(sqrtf(xs), MINV);
        float xn0;
        if (FUSE_EXP) {
            float tt = tanhf(un);
            float alpha = tt / un;
            if (tt > MAXNORM) alpha = MAXNORM / un;
            xn0 = alpha * un;   // ||expmap0(x)||
        } else {
            xn0 = un;
        }
        const float mvn_r = fmaxf(sqrtf(ms), MINV);
        const float t1 = tanhf(mvn_r / un * artanh_clip(xn0));
        float sC = t1 / mvn_r;
        float rn = t1;
        if (t1 > MAXNORM) { sC = MAXNORM / mvn_r; rn = MAXNORM; }  // project
        const float x2 = rn * rn;
        const float xyr = sC * xy;
        const float ca = 1.0f + 2.0f * xyr + y2;
        const float cb = 1.0f - x2;
        const float den = fmaxf(1.0f + 2.0f * xyr + x2 * y2, MINV);
        sS[r][0] = ca * sC / den;  // coeff on mv
        sS[r][1] = cb / den;       // coeff on kb
    }
    __syncthreads();

    // ---- phase B: per-row ||mobius_add||^2 from registers ----
#pragma unroll
    for (int mf = 0; mf < 2; ++mf)
#pragma unroll
        for (int rg = 0; rg < 4; ++rg) {
            const int row = mf * 16 + (lane >> 4) * 4 + rg;
            const float p = sS[row][0], q = sS[row][1];
            float os = 0.f;
#pragma unroll
            for (int nf = 0; nf < NF; ++nf) {
                const float o = fmaf(p, acc[mf][nf][rg], q * kbv[nf]);
                os = fmaf(o, o, os);
            }
#pragma unroll
            for (int mask = 1; mask < 16; mask <<= 1)
                os += __shfl_xor(os, mask, 64);
            if ((lane & 15) == 0) sRedA[row][wave] = os;
        }
    __syncthreads();

    if (t < BM) {
        const float os = sRedA[t][0] + sRedA[t][1] + sRedA[t][2] + sRedA[t][3];
        float on = fmaxf(sqrtf(os), MINV);
        float s2 = (on > MAXNORM) ? (MAXNORM / on) : 1.0f;  // project
        float yn = fmaxf(on * s2, MINV);
        sS[t][2] = artanh_clip(yn) / yn * s2;               // logmap0
    }
    __syncthreads();

    // ---- write f16 output directly from registers ----
#pragma unroll
    for (int mf = 0; mf < 2; ++mf)
#pragma unroll
        for (int rg = 0; rg < 4; ++rg) {
            const int row = mf * 16 + (lane >> 4) * 4 + rg;
            if (r0 + row < (size_t)n) {
                const float p = sS[row][0], q = sS[row][1], f = sS[row][2];
                _Float16* dst = XT + (r0 + row) * N + wave * (N / 4) + (lane & 15);
#pragma unroll
                for (int nf = 0; nf < NF; ++nf)
                    dst[nf * 16] = (_Float16)(f * fmaf(p, acc[mf][nf][rg], q * kbv[nf]));
            }
        }
}

// ---------------- CSR build ----------------
__global__ void count_in_kernel(const int* __restrict__ col, int E, int* __restrict__ icnt) {
    int e = blockIdx.x * 256 + threadIdx.x;
    if (e < E) atomicAdd(&icnt[col[e]], 1);
}

// dis = rsqrt(icnt+1); offs/cursor via atomic range assignment (order-free)
__global__ void dis_kernel(const int* __restrict__ icnt, float* __restrict__ dis,
                           int* __restrict__ offs, int* __restrict__ cursor,
                           int* __restrict__ gcnt, int n) {
    int i = blockIdx.x * 256 + threadIdx.x;
    if (i < n) {
        int c = icnt[i];
        dis[i] = rsqrtf((float)(c + 1));
        int p = atomicAdd(gcnt, c);
        offs[i] = p;
        cursor[i] = p;
    }
}

__global__ void csr_scatter(const int* __restrict__ row, const int* __restrict__ col,
                            const float* __restrict__ dis, int E,
                            int* __restrict__ cursor, int* __restrict__ csr_src,
                            float* __restrict__ csr_w) {
    int e = blockIdx.x * 256 + threadIdx.x;
    if (e >= E) return;
    int r = row[e], c = col[e];
    int p = atomicAdd(&cursor[c], 1);
    csr_src[p] = r;
    csr_w[p] = dis[r] * dis[c];
}

// ---------------- gather (f16 rows) + expmap0: one wave per node ----------
template <int D>
__global__ __launch_bounds__(256) void gather_expmap_kernel(
        const _Float16* __restrict__ xt, const float* __restrict__ dis,
        const int* __restrict__ offs, const int* __restrict__ icnt,
        const int* __restrict__ csr_src, const float* __restrict__ csr_w,
        int n, float* __restrict__ out) {
    constexpr int PER = D / 64;  // 4 (D=256) or 2 (D=128)
    int node = blockIdx.x * 4 + (threadIdx.x >> 6);
    if (node >= n) return;
    int lid = threadIdx.x & 63;
    const int loff = lid * PER;

    float acc[PER];
    float wc = dis[node];
    float wself = wc * wc;
    if constexpr (PER == 4) {
        const h16x4 v = *reinterpret_cast<const h16x4*>(xt + (size_t)node * D + loff);
#pragma unroll
        for (int q = 0; q < 4; ++q) acc[q] = wself * (float)v[q];
    } else {
        const h16x2 v = *reinterpret_cast<const h16x2*>(xt + (size_t)node * D + loff);
#pragma unroll
        for (int q = 0; q < 2; ++q) acc[q] = wself * (float)v[q];
    }

    const int s = offs[node];
    const int e = s + icnt[node];
    int p = s;
    // 4-wide: issue all index+row loads before accumulating (MLP)
    for (; p + 4 <= e; p += 4) {
        const int ia = csr_src[p], ib = csr_src[p + 1], ic = csr_src[p + 2], id = csr_src[p + 3];
        const float wa = csr_w[p], wb = csr_w[p + 1], wcc = csr_w[p + 2], wd = csr_w[p + 3];
        if constexpr (PER == 4) {
            const h16x4 va = *reinterpret_cast<const h16x4*>(xt + (size_t)ia * D + loff);
            const h16x4 vb = *reinterpret_cast<const h16x4*>(xt + (size_t)ib * D + loff);
            const h16x4 vc = *reinterpret_cast<const h16x4*>(xt + (size_t)ic * D + loff);
            const h16x4 vd = *reinterpret_cast<const h16x4*>(xt + (size_t)id * D + loff);
#pragma unroll
            for (int q = 0; q < 4; ++q) {
                acc[q] = fmaf(wa, (float)va[q], acc[q]);
                acc[q] = fmaf(wb, (float)vb[q], acc[q]);
                acc[q] = fmaf(wcc, (float)vc[q], acc[q]);
                acc[q] = fmaf(wd, (float)vd[q], acc[q]);
            }
        } else {
            const h16x2 va = *reinterpret_cast<const h16x2*>(xt + (size_t)ia * D + loff);
            const h16x2 vb = *reinterpret_cast<const h16x2*>(xt + (size_t)ib * D + loff);
            const h16x2 vc = *reinterpret_cast<const h16x2*>(xt + (size_t)ic * D + loff);
            const h16x2 vd = *reinterpret_cast<const h16x2*>(xt + (size_t)id * D + loff);
#pragma unroll
            for (int q = 0; q < 2; ++q) {
                acc[q] = fmaf(wa, (float)va[q], acc[q]);
                acc[q] = fmaf(wb, (float)vb[q], acc[q]);
                acc[q] = fmaf(wcc, (float)vc[q], acc[q]);
                acc[q] = fmaf(wd, (float)vd[q], acc[q]);
            }
        }
    }
    for (; p < e; ++p) {
        const int rv = csr_src[p];
        const float w = csr_w[p];
        if constexpr (PER == 4) {
            const h16x4 v = *reinterpret_cast<const h16x4*>(xt + (size_t)rv * D + loff);
#pragma unroll
            for (int q = 0; q < 4; ++q) acc[q] = fmaf(w, (float)v[q], acc[q]);
        } else {
            const h16x2 v = *reinterpret_cast<const h16x2*>(xt + (size_t)rv * D + loff);
#pragma unroll
            for (int q = 0; q < 2; ++q) acc[q] = fmaf(w, (float)v[q], acc[q]);
        }
    }

    // expmap0 in-register
    float ss = 0;
#pragma unroll
    for (int q = 0; q < PER; ++q) ss += acc[q] * acc[q];
    ss = waveAllSum(ss);
    float un = fmaxf(sqrtf(ss), MINV);
    float t = tanhf(un);
    float sc = t / un;
    if (t > MAXNORM) sc *= MAXNORM / t;

    float* op = out + (size_t)node * D + loff;
    if constexpr (PER == 4) {
        float4 o;
        o.x = sc * acc[0]; o.y = sc * acc[1]; o.z = sc * acc[2]; o.w = sc * acc[3];
        *reinterpret_cast<float4*>(op) = o;
    } else {
        float2 o;
        o.x = sc * acc[0]; o.y = sc * acc[1];
        *reinterpret_cast<float2*>(op) = o;
    }
}

extern "C" void kernel_launch(void* const* d_in, const int* in_sizes, int n_in,
                              void* d_out, int out_size, void* d_ws, size_t ws_size,
                              hipStream_t stream) {
    const float* x  = (const float*)d_in[0];
    const float* W1 = (const float*)d_in[1];
    const float* b1 = (const float*)d_in[2];
    const float* W2 = (const float*)d_in[3];
    const float* b2 = (const float*)d_in[4];
    const int*   ei = (const int*)d_in[5];

    const int N = in_sizes[0] / 256;
    const int E = in_sizes[5] / 2;
    const int* row = ei;
    const int* col = ei + E;

    float* ws = (float*)d_ws;
    size_t off = 0;
    float* A      = ws + off; off += (size_t)N * 256;            // f32 h buffer
    _Float16* C   = (_Float16*)(ws + off); off += (size_t)N * 128; // f16 xt
    f16x8* Wp1    = (f16x8*)(ws + off); off += 256 * 256;
    f16x8* Wp2    = (f16x8*)(ws + off); off += 128 * 256;
    float* kb1    = ws + off; off += 256;
    float* kb2    = ws + off; off += 128;
    float* y2s    = ws + off; off += 4;
    float* dis    = ws + off; off += N;
    int*  icnt    = (int*)(ws + off); off += N;
    int*  gcnt    = (int*)(ws + off); off += 4;
    int*  offs    = (int*)(ws + off); off += N;
    int*  cursor  = (int*)(ws + off); off += N;
    int*  csrs    = (int*)(ws + off); off += E;
    float* csrw   = ws + off; off += E;

    // weight prep + bias maps (fused launches)
    pack_w_both<<<(384 * 32 + 255) / 256, 256, 0, stream>>>(W1, Wp1, W2, Wp2);
    kb_both<<<2, 256, 0, stream>>>(b1, kb1, b2, kb2, y2s);

    // CSR build: in-degree -> atomic range assignment -> scatter
    hipMemsetAsync(icnt, 0, (size_t)(N + 4) * sizeof(int), stream);  // icnt + gcnt
    count_in_kernel<<<(E + 255) / 256, 256, 0, stream>>>(col, E, icnt);
    dis_kernel<<<(N + 255) / 256, 256, 0, stream>>>(icnt, dis, offs, cursor, gcnt, N);
    csr_scatter<<<(E + 255) / 256, 256, 0, stream>>>(row, col, dis, E, cursor, csrs, csrw);

    const int nblk = (N + 31) / 32;
    // ----- layer 1 (N=256, fused expmap0 on raw x) -----
    mfma_layer_kernel<256, true><<<nblk, 256, 0, stream>>>(x, Wp1, kb1, y2s, C, N);
    gather_expmap_kernel<256><<<(N + 3) / 4, 256, 0, stream>>>(C, dis, offs, icnt, csrs, csrw, N, A);

    // ----- layer 2 (N=128) -----
    mfma_layer_kernel<128, false><<<nblk, 256, 0, stream>>>(A, Wp2, kb2, y2s + 1, C, N);
    gather_expmap_kernel<128><<<(N + 3) / 4, 256, 0, stream>>>(C, dis, offs, icnt, csrs, csrw, N, (float*)d_out);
}